// Round 8
// baseline (252.760 us; speedup 1.0000x reference)
//
#include <hip/hip_runtime.h>
#include <stdint.h>

#define T_DIM 256
#define K_DIM 3072
#define N_DIM 3072
#define R_DIM 32
#define KG    48      // K / GROUP
#define NSPLIT 6      // gemm k-splits (8 chunks each; split 5 owns lora tail)

#define GRID_BLOCKS 576   // 48 nblk x 2 mblk x 6 split — <= 768 co-resident slots
                          // at __launch_bounds__(256,3) => barrier is starvation-free

typedef __bf16 bf16x8 __attribute__((ext_vector_type(8)));
typedef float  f32x4  __attribute__((ext_vector_type(4)));
typedef unsigned short u16x8 __attribute__((ext_vector_type(8)));

// round-to-nearest-even fp32 -> bf16 (raw ushort) — quant_act path
__device__ __forceinline__ unsigned short f2bf(float f) {
    unsigned u = __builtin_bit_cast(unsigned, f);
    unsigned rounding = 0x7FFFu + ((u >> 16) & 1u);
    return (unsigned short)((u + rounding) >> 16);
}

__device__ __forceinline__ bf16x8 cvt8(const float* p) {
    float4 lo = ((const float4*)p)[0], hi = ((const float4*)p)[1];
    bf16x8 v;
    v[0] = (__bf16)lo.x; v[1] = (__bf16)lo.y; v[2] = (__bf16)lo.z; v[3] = (__bf16)lo.w;
    v[4] = (__bf16)hi.x; v[5] = (__bf16)hi.y; v[6] = (__bf16)hi.z; v[7] = (__bf16)hi.w;
    return v;
}

// software grid barrier: device-scope release arrive + acquire spin (G16).
// Timeout escape (~170ms) turns a would-be hang into a correctness failure.
__device__ __forceinline__ void grid_barrier(unsigned* cell) {
    __syncthreads();
    if (threadIdx.x == 0) {
        __hip_atomic_fetch_add(cell, 1u, __ATOMIC_RELEASE, __HIP_MEMORY_SCOPE_AGENT);
        unsigned long long t0 = __builtin_amdgcn_s_memrealtime();
        while (__hip_atomic_load(cell, __ATOMIC_ACQUIRE, __HIP_MEMORY_SCOPE_AGENT)
               < (unsigned)GRID_BLOCKS) {
            __builtin_amdgcn_s_sleep(8);
            if (__builtin_amdgcn_s_memrealtime() - t0 > (1ULL << 24)) break;
        }
    }
    __syncthreads();
}

// ---------------- persistent fused kernel: prep | lora_mid | gemm -----------
// Phase A: pack_qw + quant_act + bias->out + Lm zero   (all 576 blocks)
// Phase B: lora_mid partials (blocks 0..95)
// Phase C: gemm, blk -> (split, mblk, nblk) — R1/R6-proven body verbatim
__global__ __launch_bounds__(256, 3) void fused(
        const float* __restrict__ x,         // [T][K]
        const int*   __restrict__ qweight,   // [N][K] codes 0..15
        const float* __restrict__ wscales,   // [N][48]
        const float* __restrict__ lora_down, // [R][K]
        const float* __restrict__ lora_up,   // [N][32]
        const float* __restrict__ bias,      // [N]
        unsigned*       __restrict__ Qp,     // [48][N][8] packed words
        unsigned short* __restrict__ Ap,     // [48][8][256][8] bf16 units
        float*          __restrict__ Lm,     // [T][32] fp32
        unsigned*       __restrict__ bar,    // [2] barrier cells (pre-zeroed)
        float*          __restrict__ out) {  // [T][N] fp32
    __shared__ uint4 BsU[2][512];    // gemm phase: [u(8)][n(64)], dbuf 16 KB
    const int blk = blockIdx.x;
    const int tid = threadIdx.x;

    // ======================= Phase A =======================
    {   // ---- pack qweight -> nibbles, OUTPUT-major: 8 units/block ----
        #pragma unroll
        for (int i = 0; i < 8; ++i) {
            size_t o = ((size_t)blk * 8 + i) * 256 + tid;  // word in [48][3072][8]
            unsigned kt  = (unsigned)(o / 24576u);         // / (N*8)
            unsigned rem = (unsigned)(o % 24576u);
            unsigned n = rem >> 3, wi = rem & 7;
            const int4* p = (const int4*)(qweight + (size_t)n * K_DIM + (size_t)kt * 64 + wi * 8);
            int4 a = p[0], b = p[1];
            unsigned w = (unsigned)(a.x & 15)        | ((unsigned)(a.y & 15) << 4)
                       | ((unsigned)(a.z & 15) << 8) | ((unsigned)(a.w & 15) << 12)
                       | ((unsigned)(b.x & 15) << 16)| ((unsigned)(b.y & 15) << 20)
                       | ((unsigned)(b.z & 15) << 24)| ((unsigned)(b.w & 15) << 28);
            Qp[o] = w;
        }
    }
    {   // ---- per-(token,group) fake-quant -> Ap unit-major: per-wave strided ----
        int lane = tid & 63;
        int wgl  = blk * 4 + (tid >> 6);                   // 0..2303
        for (int u = wgl; u < T_DIM * KG; u += GRID_BLOCKS * 4) {
            int t = u / KG, g = u % KG;
            float v = x[(size_t)t * K_DIM + g * 64 + lane];
            float a = fabsf(v);
            #pragma unroll
            for (int off = 32; off; off >>= 1) a = fmaxf(a, __shfl_xor(a, off));
            float scale = fmaxf(a / 7.0f, 1e-8f);
            float q = rintf(v / scale);
            q = fminf(fmaxf(q, -8.f), 7.f);
            Ap[(((size_t)g * 8 + (lane >> 3)) * 256 + t) * 8 + (lane & 7)] = f2bf(q * scale);
        }
    }
    {   // ---- bias -> out (assignment; idempotent across replays) ----
        for (int u = blk * 256 + tid; u < T_DIM * N_DIM / 4; u += GRID_BLOCKS * 256) {
            float4 bv = *(const float4*)&bias[(u * 4) % N_DIM];
            ((float4*)out)[u] = bv;
        }
    }
    if (blk < 32) Lm[blk * 256 + tid] = 0.f;   // Lm zero (replaces memset)

    grid_barrier(&bar[0]);

    // ======================= Phase B: lora_mid =======================
    if (blk < 96) {
        int kb = blk;
        int lane = tid & 63, wv = tid >> 6;
        int mrow = lane & 15, quad = lane >> 4;
        int k0 = kb * 32 + quad * 8;
        bf16x8 a[4], b[2];
        #pragma unroll
        for (int mt = 0; mt < 4; ++mt)
            a[mt] = cvt8(x + (size_t)(wv * 64 + mt * 16 + mrow) * K_DIM + k0);
        #pragma unroll
        for (int nt = 0; nt < 2; ++nt)
            b[nt] = cvt8(lora_down + (size_t)(nt * 16 + mrow) * K_DIM + k0);
        f32x4 acc[4][2];
        f32x4 zero = {0.f, 0.f, 0.f, 0.f};
        #pragma unroll
        for (int i = 0; i < 4; ++i) { acc[i][0] = zero; acc[i][1] = zero; }
        #pragma unroll
        for (int mt = 0; mt < 4; ++mt)
            #pragma unroll
            for (int nt = 0; nt < 2; ++nt)
                acc[mt][nt] = __builtin_amdgcn_mfma_f32_16x16x32_bf16(
                    a[mt], b[nt], acc[mt][nt], 0, 0, 0);
        #pragma unroll
        for (int mt = 0; mt < 4; ++mt)
            #pragma unroll
            for (int nt = 0; nt < 2; ++nt)
                #pragma unroll
                for (int r = 0; r < 4; ++r)
                    atomicAdd(&Lm[(size_t)(wv * 64 + mt * 16 + quad * 4 + r) * R_DIM
                                  + nt * 16 + mrow], acc[mt][nt][r]);
    }

    grid_barrier(&bar[1]);

    // ======================= Phase C: gemm (R6-proven body) =======================
    {
        const uint4* ApU = (const uint4*)Ap;
        int split = blk / 96;                 // 0..5
        int rem   = blk % 96;
        int nblk  = rem % 48;
        int mblk  = rem / 48;
        int c0 = split * (KG / NSPLIT);
        int c1 = (split == NSPLIT - 1) ? KG + 1 : c0 + (KG / NSPLIT);  // last owns lora tail
        int lane = tid & 63, wv = tid >> 6;
        int mrow = lane & 15, quad = lane >> 4;
        int n_row = tid >> 2, seg = tid & 3;
        const int nbase = nblk * 64;
        const int mbase = mblk * 128 + wv * 32;

        f32x4 acc[2][4];
        f32x4 zero = {0.f, 0.f, 0.f, 0.f};
        #pragma unroll
        for (int i = 0; i < 2; ++i)
            #pragma unroll
            for (int j = 0; j < 4; ++j) acc[i][j] = zero;

        uint2 ubc[2];        // distance-2 packed-code prefetch (constexpr-indexed)
        float wsr[2];
        bf16x8 af[2][2][2];  // [buf][ks][mt] A fragments (constexpr-indexed)

        const float* wsrow = wscales + (size_t)(nbase + n_row) * KG;

        // A-frag: unit u = ks*4 + quad, t = mbase + mt*16 + mrow
        #define AFRAG(kt, ks, mt) \
            (*(const bf16x8*)&ApU[(size_t)(kt) * 2048 + ((ks) * 4 + quad) * 256 + \
                                  mbase + (mt) * 16 + mrow])

        // prologue
        {
            #pragma unroll
            for (int ks = 0; ks < 2; ++ks)
                #pragma unroll
                for (int mt = 0; mt < 2; ++mt)
                    af[0][ks][mt] = AFRAG(c0, ks, mt);
            const unsigned* q0 = Qp + ((size_t)c0 * N_DIM + nbase + n_row) * 8 + seg * 2;
            const unsigned* q1 = Qp + ((size_t)(c0 + 1) * N_DIM + nbase + n_row) * 8 + seg * 2;
            ubc[0] = *(const uint2*)q0;
            ubc[1] = *(const uint2*)q1;
            wsr[0] = wsrow[c0];
            wsr[1] = wsrow[c0 + 1];
        }

        // one pipeline step at COMPILE-TIME parity PP; local var is kk (NOT kt)
        #define STEP(PP, KT)                                                          \
        {                                                                             \
            constexpr int p = (PP);                                                   \
            const int kk = (KT);                                                      \
            if (kk < KG) {                                                            \
                float w = wsr[p];                                                     \
                float m8w = -8.0f * w;                                                \
                unsigned u0 = ubc[p].x, u1 = ubc[p].y;                                \
                unsigned e0 = u0 & 0x0F0F0F0Fu, od0 = (u0 >> 4) & 0x0F0F0F0Fu;        \
                unsigned e1 = u1 & 0x0F0F0F0Fu, od1 = (u1 >> 4) & 0x0F0F0F0Fu;        \
                bf16x8 v0, v1;                                                        \
                _Pragma("unroll")                                                     \
                for (int j = 0; j < 4; ++j) {                                         \
                    v0[2*j]   = (__bf16)__builtin_fmaf((float)((e0  >> (8*j)) & 0xFFu), w, m8w); \
                    v0[2*j+1] = (__bf16)__builtin_fmaf((float)((od0 >> (8*j)) & 0xFFu), w, m8w); \
                    v1[2*j]   = (__bf16)__builtin_fmaf((float)((e1  >> (8*j)) & 0xFFu), w, m8w); \
                    v1[2*j+1] = (__bf16)__builtin_fmaf((float)((od1 >> (8*j)) & 0xFFu), w, m8w); \
                }                                                                     \
                BsU[p][(seg * 2 + 0) * 64 + n_row] = __builtin_bit_cast(uint4, v0);   \
                BsU[p][(seg * 2 + 1) * 64 + n_row] = __builtin_bit_cast(uint4, v1);   \
            } else {                                                                  \
                bf16x8 v0 = __builtin_bit_cast(bf16x8, (u16x8)(0));                   \
                bf16x8 v1 = __builtin_bit_cast(bf16x8, (u16x8)(0));                   \
                if (seg < 2) {                                                        \
                    const float* lu = lora_up + (size_t)(nbase + n_row) * R_DIM + seg * 16; \
                    _Pragma("unroll")                                                 \
                    for (int j = 0; j < 8; ++j) {                                     \
                        v0[j] = (__bf16)lu[j];                                        \
                        v1[j] = (__bf16)lu[8 + j];                                    \
                    }                                                                 \
                }                                                                     \
                BsU[p][(seg * 2 + 0) * 64 + n_row] = __builtin_bit_cast(uint4, v0);   \
                BsU[p][(seg * 2 + 1) * 64 + n_row] = __builtin_bit_cast(uint4, v1);   \
            }                                                                         \
            __syncthreads();                                                          \
            if (kk + 2 < c1 && kk + 2 < KG) {                                         \
                const unsigned* q2 = Qp + ((size_t)(kk + 2) * N_DIM + nbase + n_row) * 8 + seg * 2; \
                ubc[p] = *(const uint2*)q2;                                           \
                wsr[p] = wsrow[kk + 2];                                               \
            }                                                                         \
            if (kk + 1 < c1) {                                                        \
                if (kk + 1 < KG) {                                                    \
                    _Pragma("unroll")                                                 \
                    for (int ks = 0; ks < 2; ++ks)                                    \
                        _Pragma("unroll")                                             \
                        for (int mt = 0; mt < 2; ++mt)                                \
                            af[p ^ 1][ks][mt] = AFRAG(kk + 1, ks, mt);                \
                } else {                                                              \
                    _Pragma("unroll")                                                 \
                    for (int mt = 0; mt < 2; ++mt) {                                  \
                        int row = mbase + mt * 16 + mrow;                             \
                        if (quad < 4)                                                 \
                            af[p ^ 1][0][mt] = cvt8(Lm + (size_t)row * R_DIM + quad * 8); \
                        else                                                          \
                            af[p ^ 1][0][mt] = __builtin_bit_cast(bf16x8, (u16x8)(0)); \
                        af[p ^ 1][1][mt] = __builtin_bit_cast(bf16x8, (u16x8)(0));    \
                    }                                                                 \
                }                                                                     \
            }                                                                         \
            _Pragma("unroll")                                                         \
            for (int ks = 0; ks < 2; ++ks) {                                          \
                bf16x8 b[4];                                                          \
                _Pragma("unroll")                                                     \
                for (int nt = 0; nt < 4; ++nt) {                                      \
                    uint4 tb = BsU[p][(ks * 4 + quad) * 64 + nt * 16 + mrow];         \
                    b[nt] = __builtin_bit_cast(bf16x8, tb);                           \
                }                                                                     \
                _Pragma("unroll")                                                     \
                for (int mt = 0; mt < 2; ++mt)                                        \
                    _Pragma("unroll")                                                 \
                    for (int nt = 0; nt < 4; ++nt)                                    \
                        acc[mt][nt] = __builtin_amdgcn_mfma_f32_16x16x32_bf16(        \
                            af[p][ks][mt], b[nt], acc[mt][nt], 0, 0, 0);              \
            }                                                                         \
        }

        int kt = c0;
        for (; kt + 1 < c1; kt += 2) {
            STEP(0, kt);
            STEP(1, kt + 1);
        }
        if (kt < c1) STEP(0, kt);    // odd chunk count (split 5's lora tail)

        #undef STEP
        #undef AFRAG

        // epilogue: atomic accumulation into out (bias pre-written in phase A)
        #pragma unroll
        for (int nt = 0; nt < 4; ++nt) {
            int n = nbase + nt * 16 + mrow;             // C col = lane & 15
            #pragma unroll
            for (int mt = 0; mt < 2; ++mt) {
                int row0 = mblk * 128 + wv * 32 + mt * 16 + quad * 4;
                #pragma unroll
                for (int r = 0; r < 4; ++r)
                    atomicAdd(&out[(size_t)(row0 + r) * N_DIM + n], acc[mt][nt][r]);
            }
        }
    }
}

extern "C" void kernel_launch(void* const* d_in, const int* in_sizes, int n_in,
                              void* d_out, int out_size, void* d_ws, size_t ws_size,
                              hipStream_t stream) {
    const float* x         = (const float*)d_in[0];
    const int*   qweight   = (const int*)d_in[1];
    const float* wscales   = (const float*)d_in[2];
    const float* lora_down = (const float*)d_in[3];
    const float* lora_up   = (const float*)d_in[4];
    const float* bias      = (const float*)d_in[5];

    char* wsp = (char*)d_ws;
    unsigned short* Ap = (unsigned short*)wsp;                 // 48*2048*16 B
    wsp += (size_t)KG * 2048 * 16;
    float* Lm = (float*)wsp;                                   // 256*32*4 B
    wsp += (size_t)T_DIM * R_DIM * 4;
    unsigned* Qp = (unsigned*)wsp;                             // N*K/8*4 B
    wsp += (size_t)N_DIM * (K_DIM / 8) * 4;
    unsigned* bar = (unsigned*)wsp;                            // 64 B barrier cells

    hipMemsetAsync(bar, 0, 64, stream);
    fused<<<GRID_BLOCKS, 256, 0, stream>>>(
        x, qweight, wscales, lora_down, lora_up, bias,
        Qp, Ap, Lm, bar, (float*)d_out);
}

// Round 9
// 116.486 us; speedup vs baseline: 2.1699x; 2.1699x over previous
//
#include <hip/hip_runtime.h>
#include <stdint.h>

#define T_DIM 256
#define K_DIM 3072
#define N_DIM 3072
#define R_DIM 32
#define KG    48      // K / GROUP
#define NSPLIT 6      // gemm k-splits; partial sums atomicAdd'd into out

#define QA_BLOCKS 3072   // quant_act: T*KG waves, 4 waves/block
#define LM_BLOCKS 96     // lora_mid:  K/32
#define BO_BLOCKS 768    // bias_out:  T*N/4 / 256

typedef __bf16 bf16x8 __attribute__((ext_vector_type(8)));
typedef float  f32x4  __attribute__((ext_vector_type(4)));
typedef unsigned short u16x8 __attribute__((ext_vector_type(8)));

// round-to-nearest-even fp32 -> bf16 (raw ushort) — quant_act path
__device__ __forceinline__ unsigned short f2bf(float f) {
    unsigned u = __builtin_bit_cast(unsigned, f);
    unsigned rounding = 0x7FFFu + ((u >> 16) & 1u);
    return (unsigned short)((u + rounding) >> 16);
}

__device__ __forceinline__ bf16x8 cvt8(const float* p) {
    float4 lo = ((const float4*)p)[0], hi = ((const float4*)p)[1];
    bf16x8 v;
    v[0] = (__bf16)lo.x; v[1] = (__bf16)lo.y; v[2] = (__bf16)lo.z; v[3] = (__bf16)lo.w;
    v[4] = (__bf16)hi.x; v[5] = (__bf16)hi.y; v[6] = (__bf16)hi.z; v[7] = (__bf16)hi.w;
    return v;
}

// -------- prep kernel: quant_act | lora_mid | bias_out (pack branch DELETED:
// gemm now dequants straight from qweight int32 codes — R8 showed dispatch
// gaps ~0 and kernel time ~42us; pack's 42 MB traffic was its biggest slice) --
__global__ __launch_bounds__(256) void prep(
        const float* __restrict__ x,         // [T][K]
        const float* __restrict__ lora_down, // [R][K]
        const float* __restrict__ bias,      // [N]
        unsigned short* __restrict__ Ap,     // [48][8][256][8] bf16 units
        float*          __restrict__ Lm,     // [T][R] fp32 (pre-zeroed)
        float*          __restrict__ out) {  // [T][N] fp32 <- bias (gemm adds)
    int blk = blockIdx.x;
    if (blk < QA_BLOCKS) {
        // ---- per-(token,group) fake-quant -> Ap unit-major ----
        int widx = blk * 4 + (threadIdx.x >> 6);   // 0..T*KG-1
        int lane = threadIdx.x & 63;
        int t = widx / KG, g = widx % KG;
        float v = x[(size_t)t * K_DIM + g * 64 + lane];
        float a = fabsf(v);
        #pragma unroll
        for (int off = 32; off; off >>= 1) a = fmaxf(a, __shfl_xor(a, off));
        float scale = fmaxf(a / 7.0f, 1e-8f);
        float q = rintf(v / scale);
        q = fminf(fmaxf(q, -8.f), 7.f);
        Ap[(((size_t)g * 8 + (lane >> 3)) * 256 + t) * 8 + (lane & 7)] = f2bf(q * scale);
    } else if (blk < QA_BLOCKS + LM_BLOCKS) {
        // ---- lora_mid partial: one 32-wide k-step per block ----
        int kb = blk - QA_BLOCKS;
        int lane = threadIdx.x & 63, wv = threadIdx.x >> 6;
        int mrow = lane & 15, quad = lane >> 4;
        int k0 = kb * 32 + quad * 8;
        bf16x8 a[4], b[2];
        #pragma unroll
        for (int mt = 0; mt < 4; ++mt)
            a[mt] = cvt8(x + (size_t)(wv * 64 + mt * 16 + mrow) * K_DIM + k0);
        #pragma unroll
        for (int nt = 0; nt < 2; ++nt)
            b[nt] = cvt8(lora_down + (size_t)(nt * 16 + mrow) * K_DIM + k0);
        f32x4 acc[4][2];
        f32x4 zero = {0.f, 0.f, 0.f, 0.f};
        #pragma unroll
        for (int i = 0; i < 4; ++i) { acc[i][0] = zero; acc[i][1] = zero; }
        #pragma unroll
        for (int mt = 0; mt < 4; ++mt)
            #pragma unroll
            for (int nt = 0; nt < 2; ++nt)
                acc[mt][nt] = __builtin_amdgcn_mfma_f32_16x16x32_bf16(
                    a[mt], b[nt], acc[mt][nt], 0, 0, 0);
        #pragma unroll
        for (int mt = 0; mt < 4; ++mt)
            #pragma unroll
            for (int nt = 0; nt < 2; ++nt)
                #pragma unroll
                for (int r = 0; r < 4; ++r)
                    atomicAdd(&Lm[(size_t)(wv * 64 + mt * 16 + quad * 4 + r) * R_DIM
                                  + nt * 16 + mrow], acc[mt][nt][r]);
    } else {
        // ---- bias_out: out = bias (assignment: idempotent across iterations) --
        int i = (blk - QA_BLOCKS - LM_BLOCKS) * 256 + threadIdx.x;
        float4 bv = *(const float4*)&bias[(i * 4) % N_DIM];
        ((float4*)out)[i] = bv;
    }
}

// ---------------- gemm: direct-qweight dequant, LDS-B, atomic epilogue ------
// grid (48 nblk, 2 mblk, NSPLIT). M-tile 128, N-tile 64, K-chunk 64.
// Thread (n_row, seg) loads 4 x int4 codes (k = kt*64 + seg*16 .. +15) and
// dequants with cvt_f32_i32 + fma — fewer VALU than the old nibble path.
__global__ __launch_bounds__(256) void gemm_main(
        const uint4*    __restrict__ ApU,     // [48][8][256] 16B units
        const int*      __restrict__ qweight, // [N][K] codes 0..15
        const float*    __restrict__ wscales, // [N][48]
        const float*    __restrict__ Lm,      // [T][32] fp32
        const float*    __restrict__ lora_up, // [N][32] fp32
        float*          __restrict__ out) {   // [T][N] fp32 accumulators
    __shared__ uint4 BsU[2][512];    // [u(8)][n(64)], dbuf: 16 KB
    int nblk  = blockIdx.x;          // 0..47
    int mblk  = blockIdx.y;          // 0..1
    int split = blockIdx.z;          // 0..NSPLIT-1
    int c0 = split * (KG / NSPLIT);
    int c1 = (split == NSPLIT - 1) ? KG + 1 : c0 + (KG / NSPLIT);  // last owns lora tail
    int tid = threadIdx.x;
    int lane = tid & 63, wv = tid >> 6;
    int mrow = lane & 15, quad = lane >> 4;
    int n_row = tid >> 2, seg = tid & 3;
    const int nbase = nblk * 64;
    const int mbase = mblk * 128 + wv * 32;

    f32x4 acc[2][4];
    f32x4 zero = {0.f, 0.f, 0.f, 0.f};
    #pragma unroll
    for (int i = 0; i < 2; ++i)
        #pragma unroll
        for (int j = 0; j < 4; ++j) acc[i][j] = zero;

    int4  qc[2][4];      // distance-2 code prefetch (constexpr parity, const idx)
    float wsr[2];
    bf16x8 af[2][2][2];  // [buf][ks][mt] A fragments (constexpr-indexed)

    const float* wsrow = wscales + (size_t)(nbase + n_row) * KG;
    // per-thread code row: 16 consecutive codes starting at seg*16 within chunk
    const int4* qrow = (const int4*)(qweight + (size_t)(nbase + n_row) * K_DIM + seg * 16);
    // chunk kt -> qrow + kt*16 (64 ints = 16 int4s per chunk row)

    // A-frag: unit u = ks*4 + quad, t = mbase + mt*16 + mrow
    #define AFRAG(kt, ks, mt) \
        (*(const bf16x8*)&ApU[(size_t)(kt) * 2048 + ((ks) * 4 + quad) * 256 + \
                              mbase + (mt) * 16 + mrow])

    // prologue
    {
        #pragma unroll
        for (int ks = 0; ks < 2; ++ks)
            #pragma unroll
            for (int mt = 0; mt < 2; ++mt)
                af[0][ks][mt] = AFRAG(c0, ks, mt);
        #pragma unroll
        for (int j = 0; j < 4; ++j) {
            qc[0][j] = qrow[(size_t)c0 * 16 + j];
            qc[1][j] = qrow[(size_t)(c0 + 1) * 16 + j];
        }
        wsr[0] = wsrow[c0];
        wsr[1] = wsrow[c0 + 1];
    }

    // one pipeline step at COMPILE-TIME parity PP; local var is kk (NOT kt —
    // naming it kt would shadow the caller's kt and self-initialize: R7 bug)
    #define STEP(PP, KT)                                                          \
    {                                                                             \
        constexpr int p = (PP);                                                   \
        const int kk = (KT);                                                      \
        if (kk < KG) {                                                            \
            float w = wsr[p];                                                     \
            float m8w = -8.0f * w;                                                \
            int4 ca = qc[p][0], cb = qc[p][1], cc = qc[p][2], cd = qc[p][3];      \
            bf16x8 v0, v1;                                                        \
            v0[0] = (__bf16)__builtin_fmaf((float)ca.x, w, m8w);                  \
            v0[1] = (__bf16)__builtin_fmaf((float)ca.y, w, m8w);                  \
            v0[2] = (__bf16)__builtin_fmaf((float)ca.z, w, m8w);                  \
            v0[3] = (__bf16)__builtin_fmaf((float)ca.w, w, m8w);                  \
            v0[4] = (__bf16)__builtin_fmaf((float)cb.x, w, m8w);                  \
            v0[5] = (__bf16)__builtin_fmaf((float)cb.y, w, m8w);                  \
            v0[6] = (__bf16)__builtin_fmaf((float)cb.z, w, m8w);                  \
            v0[7] = (__bf16)__builtin_fmaf((float)cb.w, w, m8w);                  \
            v1[0] = (__bf16)__builtin_fmaf((float)cc.x, w, m8w);                  \
            v1[1] = (__bf16)__builtin_fmaf((float)cc.y, w, m8w);                  \
            v1[2] = (__bf16)__builtin_fmaf((float)cc.z, w, m8w);                  \
            v1[3] = (__bf16)__builtin_fmaf((float)cc.w, w, m8w);                  \
            v1[4] = (__bf16)__builtin_fmaf((float)cd.x, w, m8w);                  \
            v1[5] = (__bf16)__builtin_fmaf((float)cd.y, w, m8w);                  \
            v1[6] = (__bf16)__builtin_fmaf((float)cd.z, w, m8w);                  \
            v1[7] = (__bf16)__builtin_fmaf((float)cd.w, w, m8w);                  \
            BsU[p][(seg * 2 + 0) * 64 + n_row] = __builtin_bit_cast(uint4, v0);   \
            BsU[p][(seg * 2 + 1) * 64 + n_row] = __builtin_bit_cast(uint4, v1);   \
        } else {                                                                  \
            bf16x8 v0 = __builtin_bit_cast(bf16x8, (u16x8)(0));                   \
            bf16x8 v1 = __builtin_bit_cast(bf16x8, (u16x8)(0));                   \
            if (seg < 2) {                                                        \
                const float* lu = lora_up + (size_t)(nbase + n_row) * R_DIM + seg * 16; \
                _Pragma("unroll")                                                 \
                for (int j = 0; j < 8; ++j) {                                     \
                    v0[j] = (__bf16)lu[j];                                        \
                    v1[j] = (__bf16)lu[8 + j];                                    \
                }                                                                 \
            }                                                                     \
            BsU[p][(seg * 2 + 0) * 64 + n_row] = __builtin_bit_cast(uint4, v0);   \
            BsU[p][(seg * 2 + 1) * 64 + n_row] = __builtin_bit_cast(uint4, v1);   \
        }                                                                         \
        __syncthreads();                                                          \
        if (kk + 2 < c1 && kk + 2 < KG) {                                         \
            _Pragma("unroll")                                                     \
            for (int j = 0; j < 4; ++j)                                           \
                qc[p][j] = qrow[(size_t)(kk + 2) * 16 + j];                       \
            wsr[p] = wsrow[kk + 2];                                               \
        }                                                                         \
        if (kk + 1 < c1) {                                                        \
            if (kk + 1 < KG) {                                                    \
                _Pragma("unroll")                                                 \
                for (int ks = 0; ks < 2; ++ks)                                    \
                    _Pragma("unroll")                                             \
                    for (int mt = 0; mt < 2; ++mt)                                \
                        af[p ^ 1][ks][mt] = AFRAG(kk + 1, ks, mt);                \
            } else {                                                              \
                _Pragma("unroll")                                                 \
                for (int mt = 0; mt < 2; ++mt) {                                  \
                    int row = mbase + mt * 16 + mrow;                             \
                    if (quad < 4)                                                 \
                        af[p ^ 1][0][mt] = cvt8(Lm + (size_t)row * R_DIM + quad * 8); \
                    else                                                          \
                        af[p ^ 1][0][mt] = __builtin_bit_cast(bf16x8, (u16x8)(0)); \
                    af[p ^ 1][1][mt] = __builtin_bit_cast(bf16x8, (u16x8)(0));    \
                }                                                                 \
            }                                                                     \
        }                                                                         \
        _Pragma("unroll")                                                         \
        for (int ks = 0; ks < 2; ++ks) {                                          \
            bf16x8 b[4];                                                          \
            _Pragma("unroll")                                                     \
            for (int nt = 0; nt < 4; ++nt) {                                      \
                uint4 tb = BsU[p][(ks * 4 + quad) * 64 + nt * 16 + mrow];         \
                b[nt] = __builtin_bit_cast(bf16x8, tb);                           \
            }                                                                     \
            _Pragma("unroll")                                                     \
            for (int mt = 0; mt < 2; ++mt)                                        \
                _Pragma("unroll")                                                 \
                for (int nt = 0; nt < 4; ++nt)                                    \
                    acc[mt][nt] = __builtin_amdgcn_mfma_f32_16x16x32_bf16(        \
                        af[p][ks][mt], b[nt], acc[mt][nt], 0, 0, 0);              \
        }                                                                         \
    }

    int kt = c0;
    for (; kt + 1 < c1; kt += 2) {
        STEP(0, kt);
        STEP(1, kt + 1);
    }
    if (kt < c1) STEP(0, kt);    // odd chunk count (last split's lora tail)

    #undef STEP
    #undef AFRAG
    // epilogue: atomic accumulation into out (bias pre-written by prep)
    #pragma unroll
    for (int nt = 0; nt < 4; ++nt) {
        int n = nbase + nt * 16 + mrow;             // C col = lane & 15
        #pragma unroll
        for (int mt = 0; mt < 2; ++mt) {
            int row0 = mblk * 128 + wv * 32 + mt * 16 + quad * 4;
            #pragma unroll
            for (int r = 0; r < 4; ++r)
                atomicAdd(&out[(size_t)(row0 + r) * N_DIM + n], acc[mt][nt][r]);
        }
    }
}

extern "C" void kernel_launch(void* const* d_in, const int* in_sizes, int n_in,
                              void* d_out, int out_size, void* d_ws, size_t ws_size,
                              hipStream_t stream) {
    const float* x         = (const float*)d_in[0];
    const int*   qweight   = (const int*)d_in[1];
    const float* wscales   = (const float*)d_in[2];
    const float* lora_down = (const float*)d_in[3];
    const float* lora_up   = (const float*)d_in[4];
    const float* bias      = (const float*)d_in[5];

    char* wsp = (char*)d_ws;
    unsigned short* Ap = (unsigned short*)wsp;                 // 48*2048*16 B
    wsp += (size_t)KG * 2048 * 16;
    float* Lm = (float*)wsp;                                   // 256*32*4 B

    hipMemsetAsync(Lm, 0, (size_t)T_DIM * R_DIM * sizeof(float), stream);
    prep<<<QA_BLOCKS + LM_BLOCKS + BO_BLOCKS, 256, 0, stream>>>(
        x, lora_down, bias, Ap, Lm, (float*)d_out);
    gemm_main<<<dim3(48, 2, NSPLIT), 256, 0, stream>>>(
        (const uint4*)Ap, qweight, wscales, Lm, lora_up, (float*)d_out);
}